// Round 12
// baseline (34.371 us; speedup 1.0000x reference)
//
#include <hip/hip_runtime.h>

// Segment-wise attention-weighted mean.
//   avg[b][h][d]      = sum_{i in seg b} features[i][d]*att[i][h] / sum att[i][h]
//   weights_sum[b][h] = sum_{i in seg b} att[i][h]
// B=64, H=8, D=128, TOTAL=262144, segment_ids sorted.
//
// History: R4 two-stage partials 80->48.7; R5 parallel reduce ->42.2; R6
// fusion REGRESSED (fences) ->150; R7 inline lower_bound ->40.6; R8 att->LDS
// null ->40.1; R9 4-deep null ->39.8; R10 NT loads REGRESSED ->44.0 (L1
// helps; reverted). Effective read rate pinned ~4.3 TB/s across all
// structures -> likely near the pure-READ ceiling (m13's 6.29 TB/s is
// copy r+w). R11: CPS 32->16 (halve partial traffic + searches + tail;
// tests traffic-bound vs wave-starved).

constexpr int D       = 128;
constexpr int H       = 8;
constexpr int B       = 64;
constexpr int CPS     = 16;            // chunk-blocks per segment -> 1024 blocks
constexpr int PSTRIDE = H * D + H;     // 1032 floats per partial record

// --- 64-ary lane-parallel lower_bound over sorted seg ids -------------------
__device__ __forceinline__ int lower_bound64(const int* __restrict__ seg,
                                             int total, int target) {
    int lo = 0, hi = total;
    const int lane = threadIdx.x & 63;
    while (hi > lo) {
        const int span   = hi - lo;
        const int stride = (span + 63) >> 6;            // ceil(span/64)
        const int p      = lo + lane * stride;
        const bool pred  = (p < hi) && (seg[p] < target);
        unsigned long long mask = __ballot(pred);
        if (mask == 0ull) { hi = lo; break; }
        const int k = 63 - __clzll(mask);
        const int nlo = lo + k * stride + 1;
        hi = min(lo + (k + 1) * stride, hi);
        lo = nlo;
    }
    return lo;
}

// --- kernel 1: accumulate -> per-block partial record (contention-free) ----
// 256 threads = 8 groups x 32 lanes. Lane dq accumulates all 8 heads for
// dims 4dq..4dq+3. att slice staged in LDS; 4 feature rows in flight.
__global__ __launch_bounds__(256) void accum_kernel(
        const float4* __restrict__ F,     // features as float4, 32 per row
        const float4* __restrict__ A4,    // att as float4, 2 per row
        const int*    __restrict__ seg,   // sorted ids
        int total,
        float* __restrict__ partial) {    // B*CPS records of PSTRIDE floats
    const int b  = blockIdx.x / CPS;
    const int c  = blockIdx.x % CPS;
    const int s0 = lower_bound64(seg, total, b);
    const int s1 = lower_bound64(seg, total, b + 1);
    const int chunk = (s1 - s0 + CPS - 1) / CPS;
    const int r0 = s0 + c * chunk;
    const int r1 = min(r0 + chunk, s1);
    const int nrows = r1 - r0;            // may be <= 0; still flush zeros

    const int t  = threadIdx.x;
    const int dq = t & 31;   // float4 slot within row
    const int g  = t >> 5;   // row group 0..7

    // LDS: att staging buffer aliased with the cross-wave reduction scratch.
    __shared__ __align__(16) char shmem[96 * 41 * 4];
    float4* attS = (float4*)shmem;
    float (*red)[41] = (float(*)[41])shmem;
    constexpr int ATT_CAP = (96 * 41 * 4) / 16;   // 984 float4 -> nrows <= 492

    const bool useLds = (nrows > 0) && (2 * nrows <= ATT_CAP);
    if (useLds) {
        for (int j = t; j < 2 * nrows; j += 256) attS[j] = A4[(size_t)r0 * 2 + j];
    }
    __syncthreads();

    float4 acc[8];
    #pragma unroll
    for (int h = 0; h < 8; ++h) acc[h] = make_float4(0.f, 0.f, 0.f, 0.f);
    float4 wa = make_float4(0.f, 0.f, 0.f, 0.f);
    float4 wb = make_float4(0.f, 0.f, 0.f, 0.f);

#define ROW_FMA(f, a0, a1)                                                     \
    do {                                                                       \
        acc[0].x = fmaf(f.x, a0.x, acc[0].x); acc[0].y = fmaf(f.y, a0.x, acc[0].y); \
        acc[0].z = fmaf(f.z, a0.x, acc[0].z); acc[0].w = fmaf(f.w, a0.x, acc[0].w); \
        acc[1].x = fmaf(f.x, a0.y, acc[1].x); acc[1].y = fmaf(f.y, a0.y, acc[1].y); \
        acc[1].z = fmaf(f.z, a0.y, acc[1].z); acc[1].w = fmaf(f.w, a0.y, acc[1].w); \
        acc[2].x = fmaf(f.x, a0.z, acc[2].x); acc[2].y = fmaf(f.y, a0.z, acc[2].y); \
        acc[2].z = fmaf(f.z, a0.z, acc[2].z); acc[2].w = fmaf(f.w, a0.z, acc[2].w); \
        acc[3].x = fmaf(f.x, a0.w, acc[3].x); acc[3].y = fmaf(f.y, a0.w, acc[3].y); \
        acc[3].z = fmaf(f.z, a0.w, acc[3].z); acc[3].w = fmaf(f.w, a0.w, acc[3].w); \
        acc[4].x = fmaf(f.x, a1.x, acc[4].x); acc[4].y = fmaf(f.y, a1.x, acc[4].y); \
        acc[4].z = fmaf(f.z, a1.x, acc[4].z); acc[4].w = fmaf(f.w, a1.x, acc[4].w); \
        acc[5].x = fmaf(f.x, a1.y, acc[5].x); acc[5].y = fmaf(f.y, a1.y, acc[5].y); \
        acc[5].z = fmaf(f.z, a1.y, acc[5].z); acc[5].w = fmaf(f.w, a1.y, acc[5].w); \
        acc[6].x = fmaf(f.x, a1.z, acc[6].x); acc[6].y = fmaf(f.y, a1.z, acc[6].y); \
        acc[6].z = fmaf(f.z, a1.z, acc[6].z); acc[6].w = fmaf(f.w, a1.z, acc[6].w); \
        acc[7].x = fmaf(f.x, a1.w, acc[7].x); acc[7].y = fmaf(f.y, a1.w, acc[7].y); \
        acc[7].z = fmaf(f.z, a1.w, acc[7].z); acc[7].w = fmaf(f.w, a1.w, acc[7].w); \
        wa.x += a0.x; wa.y += a0.y; wa.z += a0.z; wa.w += a0.w;                \
        wb.x += a1.x; wb.y += a1.y; wb.z += a1.z; wb.w += a1.w;                \
    } while (0)

    if (useLds) {
        int j = g;
        // 4-deep pipeline: rows j, j+8, j+16, j+24 in flight (4KB/wave)
        for (; j + 24 < nrows; j += 32) {
            float4 f1 = F[(size_t)(r0 + j)      * (D / 4) + dq];
            float4 f2 = F[(size_t)(r0 + j + 8)  * (D / 4) + dq];
            float4 f3 = F[(size_t)(r0 + j + 16) * (D / 4) + dq];
            float4 f4 = F[(size_t)(r0 + j + 24) * (D / 4) + dq];
            ROW_FMA(f1, attS[2 * j + 0],        attS[2 * j + 1]);
            ROW_FMA(f2, attS[2 * (j + 8) + 0],  attS[2 * (j + 8) + 1]);
            ROW_FMA(f3, attS[2 * (j + 16) + 0], attS[2 * (j + 16) + 1]);
            ROW_FMA(f4, attS[2 * (j + 24) + 0], attS[2 * (j + 24) + 1]);
        }
        for (; j < nrows; j += 8) {
            float4 f1 = F[(size_t)(r0 + j) * (D / 4) + dq];
            ROW_FMA(f1, attS[2 * j + 0], attS[2 * j + 1]);
        }
    } else if (nrows > 0) {                     // oversized chunk fallback
        int j = g;
        for (; j + 8 < nrows; j += 16) {
            float4 f1  = F[(size_t)(r0 + j) * (D / 4) + dq];
            float4 f2  = F[(size_t)(r0 + j + 8) * (D / 4) + dq];
            float4 a10 = A4[(size_t)(r0 + j) * 2 + 0];
            float4 a11 = A4[(size_t)(r0 + j) * 2 + 1];
            float4 a20 = A4[(size_t)(r0 + j + 8) * 2 + 0];
            float4 a21 = A4[(size_t)(r0 + j + 8) * 2 + 1];
            ROW_FMA(f1, a10, a11);
            ROW_FMA(f2, a20, a21);
        }
        if (j < nrows) {
            float4 f1  = F[(size_t)(r0 + j) * (D / 4) + dq];
            float4 a10 = A4[(size_t)(r0 + j) * 2 + 0];
            float4 a11 = A4[(size_t)(r0 + j) * 2 + 1];
            ROW_FMA(f1, a10, a11);
        }
    }
#undef ROW_FMA

    __syncthreads();   // everyone done reading attS before red overwrites it

    // ---- block-internal reduce: shfl(32) then LDS across the 4 waves ------
    #pragma unroll
    for (int h = 0; h < 8; ++h) {
        acc[h].x += __shfl_down(acc[h].x, 32);
        acc[h].y += __shfl_down(acc[h].y, 32);
        acc[h].z += __shfl_down(acc[h].z, 32);
        acc[h].w += __shfl_down(acc[h].w, 32);
    }
    wa.x += __shfl_down(wa.x, 32); wa.y += __shfl_down(wa.y, 32);
    wa.z += __shfl_down(wa.z, 32); wa.w += __shfl_down(wa.w, 32);
    wb.x += __shfl_down(wb.x, 32); wb.y += __shfl_down(wb.y, 32);
    wb.z += __shfl_down(wb.z, 32); wb.w += __shfl_down(wb.w, 32);

    const int lane = t & 63;
    const int wv   = t >> 6;
    if (wv > 0 && lane < 32) {
        float* r = red[(wv - 1) * 32 + lane];
        #pragma unroll
        for (int h = 0; h < 8; ++h) {
            r[h * 4 + 0] = acc[h].x; r[h * 4 + 1] = acc[h].y;
            r[h * 4 + 2] = acc[h].z; r[h * 4 + 3] = acc[h].w;
        }
        r[32] = wa.x; r[33] = wa.y; r[34] = wa.z; r[35] = wa.w;
        r[36] = wb.x; r[37] = wb.y; r[38] = wb.z; r[39] = wb.w;
    }
    __syncthreads();
    if (wv == 0 && lane < 32) {
        #pragma unroll
        for (int j = 0; j < 3; ++j) {
            const float* r = red[j * 32 + lane];
            #pragma unroll
            for (int h = 0; h < 8; ++h) {
                acc[h].x += r[h * 4 + 0]; acc[h].y += r[h * 4 + 1];
                acc[h].z += r[h * 4 + 2]; acc[h].w += r[h * 4 + 3];
            }
            wa.x += r[32]; wa.y += r[33]; wa.z += r[34]; wa.w += r[35];
            wb.x += r[36]; wb.y += r[37]; wb.z += r[38]; wb.w += r[39];
        }
        // flush this block's partial record (contention-free plain stores)
        float4* p = (float4*)(partial + (size_t)blockIdx.x * PSTRIDE);
        #pragma unroll
        for (int h = 0; h < 8; ++h) p[h * 32 + lane] = acc[h];
        if (lane == 0) { p[256] = wa; p[257] = wb; }
    }
}

// --- kernel 2: reduce partials + divide + nan fixup --------------------------
// One block per (b,h) -> 512 blocks. Thread t sums dim t over CPS records.
__global__ __launch_bounds__(128) void reduce_kernel(
        const float* __restrict__ partial, float* __restrict__ out) {
    const int blk = blockIdx.x;          // b*H + h
    const int b   = blk >> 3;
    const int h   = blk & 7;
    const int t   = threadIdx.x;

    const float* base = partial + (size_t)b * CPS * PSTRIDE + h * D + t;
    float s = 0.f;
    #pragma unroll
    for (int c = 0; c < CPS; ++c) s += base[c * PSTRIDE];

    float w = 0.f;
    if (t < CPS)
        w = partial[((size_t)(b * CPS + t)) * PSTRIDE + H * D + h];
    if (t < 64) {
        #pragma unroll
        for (int off = 32; off >= 1; off >>= 1) w += __shfl_down(w, off);
    }
    __shared__ float wsh;
    if (t == 0) wsh = w;
    __syncthreads();

    const float denom = wsh;
    float r = (denom == 0.0f) ? 0.0f : s / denom;
    if (isnan(r)) r = 1e-5f;
    out[blk * D + t] = r;
    if (t == 0) out[B * H * D + blk] = denom;
}

// --- fallback: atomic accumulate + finalize (if ws too small) ---------------
__global__ __launch_bounds__(256) void accum_atomic_kernel(
        const float4* __restrict__ F, const float4* __restrict__ A4,
        const int* __restrict__ seg, int total, float* __restrict__ dst) {
    const int b  = blockIdx.x / CPS;
    const int c  = blockIdx.x % CPS;
    const int s0 = lower_bound64(seg, total, b);
    const int s1 = lower_bound64(seg, total, b + 1);
    const int chunk = (s1 - s0 + CPS - 1) / CPS;
    const int r0 = s0 + c * chunk;
    const int r1 = min(r0 + chunk, s1);
    const int t  = threadIdx.x;
    const int dq = t & 31;
    const int g  = t >> 5;
    float4 acc[8];
    #pragma unroll
    for (int h = 0; h < 8; ++h) acc[h] = make_float4(0.f, 0.f, 0.f, 0.f);
    float wsum[8] = {0.f};
    for (int i = r0 + g; i < r1; i += 8) {
        float4 f = F[(size_t)i * (D / 4) + dq];
        const float* a = (const float*)&A4[(size_t)i * 2];
        #pragma unroll
        for (int h = 0; h < 8; ++h) {
            acc[h].x = fmaf(f.x, a[h], acc[h].x);
            acc[h].y = fmaf(f.y, a[h], acc[h].y);
            acc[h].z = fmaf(f.z, a[h], acc[h].z);
            acc[h].w = fmaf(f.w, a[h], acc[h].w);
            wsum[h] += a[h];
        }
    }
    #pragma unroll
    for (int h = 0; h < 8; ++h) {
        float* o = dst + (b * H + h) * D + dq * 4;
        atomicAdd(o + 0, acc[h].x); atomicAdd(o + 1, acc[h].y);
        atomicAdd(o + 2, acc[h].z); atomicAdd(o + 3, acc[h].w);
        if (dq == 0) atomicAdd(dst + B * H * D + b * H + h, wsum[h]);
    }
}

__global__ void finalize_kernel(float* __restrict__ out) {
    int idx = blockIdx.x * blockDim.x + threadIdx.x;
    if (idx >= B * H * D) return;
    float denom = out[B * H * D + (idx >> 7)];
    float r = (denom == 0.0f) ? 0.0f : out[idx] / denom;
    if (isnan(r)) r = 1e-5f;
    out[idx] = r;
}

extern "C" void kernel_launch(void* const* d_in, const int* in_sizes, int n_in,
                              void* d_out, int out_size, void* d_ws, size_t ws_size,
                              hipStream_t stream) {
    const float* features = (const float*)d_in[0];
    const float* att      = (const float*)d_in[1];
    const int*   seg      = (const int*)d_in[2];
    const int    total    = in_sizes[2];

    float* partial = (float*)d_ws;
    float* out     = (float*)d_out;

    const size_t needed = (size_t)B * CPS * PSTRIDE * sizeof(float);

    if (ws_size >= needed) {
        accum_kernel<<<B * CPS, 256, 0, stream>>>(
            (const float4*)features, (const float4*)att, seg, total, partial);
        reduce_kernel<<<B * H, 128, 0, stream>>>(partial, out);
    } else {
        hipMemsetAsync(d_out, 0, (size_t)out_size * sizeof(float), stream);
        accum_atomic_kernel<<<B * CPS, 256, 0, stream>>>(
            (const float4*)features, (const float4*)att, seg, total, out);
        finalize_kernel<<<(B * H * D + 255) / 256, 256, 0, stream>>>(out);
    }
}

// Round 13
// 32.730 us; speedup vs baseline: 1.0501x; 1.0501x over previous
//
#include <hip/hip_runtime.h>

// Segment-wise attention-weighted mean.
//   avg[b][h][d]      = sum_{i in seg b} features[i][d]*att[i][h] / sum att[i][h]
//   weights_sum[b][h] = sum_{i in seg b} att[i][h]
// B=64, H=8, D=128, TOTAL=262144, segment_ids sorted.
//
// History: R4 two-stage partials 80->48.7; R5 parallel reduce ->42.2; R6
// fusion REGRESSED (fences) ->150; R7 inline lower_bound ->40.6; R8/R9
// load-structure probes null ->39.8; R10 NT loads REGRESSED ->44; R11
// CPS 32->16 ->34.4 (traffic+fixed-cost confirmed as the live lever).
// R13: CPS 16->8 (512 blocks, 2/CU). ATT LDS cap grown to 1152 f4 since
// chunks are now ~512 rows; global-att fallback guards oversize.

constexpr int D       = 128;
constexpr int H       = 8;
constexpr int B       = 64;
constexpr int CPS     = 8;             // chunk-blocks per segment -> 512 blocks
constexpr int PSTRIDE = H * D + H;     // 1032 floats per partial record

// --- 64-ary lane-parallel lower_bound over sorted seg ids -------------------
__device__ __forceinline__ int lower_bound64(const int* __restrict__ seg,
                                             int total, int target) {
    int lo = 0, hi = total;
    const int lane = threadIdx.x & 63;
    while (hi > lo) {
        const int span   = hi - lo;
        const int stride = (span + 63) >> 6;            // ceil(span/64)
        const int p      = lo + lane * stride;
        const bool pred  = (p < hi) && (seg[p] < target);
        unsigned long long mask = __ballot(pred);
        if (mask == 0ull) { hi = lo; break; }
        const int k = 63 - __clzll(mask);
        const int nlo = lo + k * stride + 1;
        hi = min(lo + (k + 1) * stride, hi);
        lo = nlo;
    }
    return lo;
}

// --- kernel 1: accumulate -> per-block partial record (contention-free) ----
// 256 threads = 8 groups x 32 lanes. Lane dq accumulates all 8 heads for
// dims 4dq..4dq+3. att slice staged in LDS; 4 feature rows in flight.
__global__ __launch_bounds__(256) void accum_kernel(
        const float4* __restrict__ F,     // features as float4, 32 per row
        const float4* __restrict__ A4,    // att as float4, 2 per row
        const int*    __restrict__ seg,   // sorted ids
        int total,
        float* __restrict__ partial) {    // B*CPS records of PSTRIDE floats
    const int b  = blockIdx.x / CPS;
    const int c  = blockIdx.x % CPS;
    const int s0 = lower_bound64(seg, total, b);
    const int s1 = lower_bound64(seg, total, b + 1);
    const int chunk = (s1 - s0 + CPS - 1) / CPS;
    const int r0 = s0 + c * chunk;
    const int r1 = min(r0 + chunk, s1);
    const int nrows = r1 - r0;            // may be <= 0; still flush zeros

    const int t  = threadIdx.x;
    const int dq = t & 31;   // float4 slot within row
    const int g  = t >> 5;   // row group 0..7

    // LDS: att staging buffer (up to 1152 f4 = 576 rows) aliased with the
    // cross-wave reduction scratch (96*41*4 = 15744 B). 18432 B total.
    __shared__ __align__(16) char shmem[18432];
    float4* attS = (float4*)shmem;
    float (*red)[41] = (float(*)[41])shmem;
    constexpr int ATT_CAP = 18432 / 16;   // 1152 float4 -> nrows <= 576

    const bool useLds = (nrows > 0) && (2 * nrows <= ATT_CAP);
    if (useLds) {
        for (int j = t; j < 2 * nrows; j += 256) attS[j] = A4[(size_t)r0 * 2 + j];
    }
    __syncthreads();

    float4 acc[8];
    #pragma unroll
    for (int h = 0; h < 8; ++h) acc[h] = make_float4(0.f, 0.f, 0.f, 0.f);
    float4 wa = make_float4(0.f, 0.f, 0.f, 0.f);
    float4 wb = make_float4(0.f, 0.f, 0.f, 0.f);

#define ROW_FMA(f, a0, a1)                                                     \
    do {                                                                       \
        acc[0].x = fmaf(f.x, a0.x, acc[0].x); acc[0].y = fmaf(f.y, a0.x, acc[0].y); \
        acc[0].z = fmaf(f.z, a0.x, acc[0].z); acc[0].w = fmaf(f.w, a0.x, acc[0].w); \
        acc[1].x = fmaf(f.x, a0.y, acc[1].x); acc[1].y = fmaf(f.y, a0.y, acc[1].y); \
        acc[1].z = fmaf(f.z, a0.y, acc[1].z); acc[1].w = fmaf(f.w, a0.y, acc[1].w); \
        acc[2].x = fmaf(f.x, a0.z, acc[2].x); acc[2].y = fmaf(f.y, a0.z, acc[2].y); \
        acc[2].z = fmaf(f.z, a0.z, acc[2].z); acc[2].w = fmaf(f.w, a0.z, acc[2].w); \
        acc[3].x = fmaf(f.x, a0.w, acc[3].x); acc[3].y = fmaf(f.y, a0.w, acc[3].y); \
        acc[3].z = fmaf(f.z, a0.w, acc[3].z); acc[3].w = fmaf(f.w, a0.w, acc[3].w); \
        acc[4].x = fmaf(f.x, a1.x, acc[4].x); acc[4].y = fmaf(f.y, a1.x, acc[4].y); \
        acc[4].z = fmaf(f.z, a1.x, acc[4].z); acc[4].w = fmaf(f.w, a1.x, acc[4].w); \
        acc[5].x = fmaf(f.x, a1.y, acc[5].x); acc[5].y = fmaf(f.y, a1.y, acc[5].y); \
        acc[5].z = fmaf(f.z, a1.y, acc[5].z); acc[5].w = fmaf(f.w, a1.y, acc[5].w); \
        acc[6].x = fmaf(f.x, a1.z, acc[6].x); acc[6].y = fmaf(f.y, a1.z, acc[6].y); \
        acc[6].z = fmaf(f.z, a1.z, acc[6].z); acc[6].w = fmaf(f.w, a1.z, acc[6].w); \
        acc[7].x = fmaf(f.x, a1.w, acc[7].x); acc[7].y = fmaf(f.y, a1.w, acc[7].y); \
        acc[7].z = fmaf(f.z, a1.w, acc[7].z); acc[7].w = fmaf(f.w, a1.w, acc[7].w); \
        wa.x += a0.x; wa.y += a0.y; wa.z += a0.z; wa.w += a0.w;                \
        wb.x += a1.x; wb.y += a1.y; wb.z += a1.z; wb.w += a1.w;                \
    } while (0)

    if (useLds) {
        int j = g;
        // 4-deep pipeline: rows j, j+8, j+16, j+24 in flight (4KB/wave)
        for (; j + 24 < nrows; j += 32) {
            float4 f1 = F[(size_t)(r0 + j)      * (D / 4) + dq];
            float4 f2 = F[(size_t)(r0 + j + 8)  * (D / 4) + dq];
            float4 f3 = F[(size_t)(r0 + j + 16) * (D / 4) + dq];
            float4 f4 = F[(size_t)(r0 + j + 24) * (D / 4) + dq];
            ROW_FMA(f1, attS[2 * j + 0],        attS[2 * j + 1]);
            ROW_FMA(f2, attS[2 * (j + 8) + 0],  attS[2 * (j + 8) + 1]);
            ROW_FMA(f3, attS[2 * (j + 16) + 0], attS[2 * (j + 16) + 1]);
            ROW_FMA(f4, attS[2 * (j + 24) + 0], attS[2 * (j + 24) + 1]);
        }
        for (; j < nrows; j += 8) {
            float4 f1 = F[(size_t)(r0 + j) * (D / 4) + dq];
            ROW_FMA(f1, attS[2 * j + 0], attS[2 * j + 1]);
        }
    } else if (nrows > 0) {                     // oversized chunk fallback
        int j = g;
        for (; j + 8 < nrows; j += 16) {
            float4 f1  = F[(size_t)(r0 + j) * (D / 4) + dq];
            float4 f2  = F[(size_t)(r0 + j + 8) * (D / 4) + dq];
            float4 a10 = A4[(size_t)(r0 + j) * 2 + 0];
            float4 a11 = A4[(size_t)(r0 + j) * 2 + 1];
            float4 a20 = A4[(size_t)(r0 + j + 8) * 2 + 0];
            float4 a21 = A4[(size_t)(r0 + j + 8) * 2 + 1];
            ROW_FMA(f1, a10, a11);
            ROW_FMA(f2, a20, a21);
        }
        if (j < nrows) {
            float4 f1  = F[(size_t)(r0 + j) * (D / 4) + dq];
            float4 a10 = A4[(size_t)(r0 + j) * 2 + 0];
            float4 a11 = A4[(size_t)(r0 + j) * 2 + 1];
            ROW_FMA(f1, a10, a11);
        }
    }
#undef ROW_FMA

    __syncthreads();   // everyone done reading attS before red overwrites it

    // ---- block-internal reduce: shfl(32) then LDS across the 4 waves ------
    #pragma unroll
    for (int h = 0; h < 8; ++h) {
        acc[h].x += __shfl_down(acc[h].x, 32);
        acc[h].y += __shfl_down(acc[h].y, 32);
        acc[h].z += __shfl_down(acc[h].z, 32);
        acc[h].w += __shfl_down(acc[h].w, 32);
    }
    wa.x += __shfl_down(wa.x, 32); wa.y += __shfl_down(wa.y, 32);
    wa.z += __shfl_down(wa.z, 32); wa.w += __shfl_down(wa.w, 32);
    wb.x += __shfl_down(wb.x, 32); wb.y += __shfl_down(wb.y, 32);
    wb.z += __shfl_down(wb.z, 32); wb.w += __shfl_down(wb.w, 32);

    const int lane = t & 63;
    const int wv   = t >> 6;
    if (wv > 0 && lane < 32) {
        float* r = red[(wv - 1) * 32 + lane];
        #pragma unroll
        for (int h = 0; h < 8; ++h) {
            r[h * 4 + 0] = acc[h].x; r[h * 4 + 1] = acc[h].y;
            r[h * 4 + 2] = acc[h].z; r[h * 4 + 3] = acc[h].w;
        }
        r[32] = wa.x; r[33] = wa.y; r[34] = wa.z; r[35] = wa.w;
        r[36] = wb.x; r[37] = wb.y; r[38] = wb.z; r[39] = wb.w;
    }
    __syncthreads();
    if (wv == 0 && lane < 32) {
        #pragma unroll
        for (int j = 0; j < 3; ++j) {
            const float* r = red[j * 32 + lane];
            #pragma unroll
            for (int h = 0; h < 8; ++h) {
                acc[h].x += r[h * 4 + 0]; acc[h].y += r[h * 4 + 1];
                acc[h].z += r[h * 4 + 2]; acc[h].w += r[h * 4 + 3];
            }
            wa.x += r[32]; wa.y += r[33]; wa.z += r[34]; wa.w += r[35];
            wb.x += r[36]; wb.y += r[37]; wb.z += r[38]; wb.w += r[39];
        }
        // flush this block's partial record (contention-free plain stores)
        float4* p = (float4*)(partial + (size_t)blockIdx.x * PSTRIDE);
        #pragma unroll
        for (int h = 0; h < 8; ++h) p[h * 32 + lane] = acc[h];
        if (lane == 0) { p[256] = wa; p[257] = wb; }
    }
}

// --- kernel 2: reduce partials + divide + nan fixup --------------------------
// One block per (b,h) -> 512 blocks. Thread t sums dim t over CPS records.
__global__ __launch_bounds__(128) void reduce_kernel(
        const float* __restrict__ partial, float* __restrict__ out) {
    const int blk = blockIdx.x;          // b*H + h
    const int b   = blk >> 3;
    const int h   = blk & 7;
    const int t   = threadIdx.x;

    const float* base = partial + (size_t)b * CPS * PSTRIDE + h * D + t;
    float s = 0.f;
    #pragma unroll
    for (int c = 0; c < CPS; ++c) s += base[c * PSTRIDE];

    float w = 0.f;
    if (t < CPS)
        w = partial[((size_t)(b * CPS + t)) * PSTRIDE + H * D + h];
    if (t < 64) {
        #pragma unroll
        for (int off = 32; off >= 1; off >>= 1) w += __shfl_down(w, off);
    }
    __shared__ float wsh;
    if (t == 0) wsh = w;
    __syncthreads();

    const float denom = wsh;
    float r = (denom == 0.0f) ? 0.0f : s / denom;
    if (isnan(r)) r = 1e-5f;
    out[blk * D + t] = r;
    if (t == 0) out[B * H * D + blk] = denom;
}

// --- fallback: atomic accumulate + finalize (if ws too small) ---------------
__global__ __launch_bounds__(256) void accum_atomic_kernel(
        const float4* __restrict__ F, const float4* __restrict__ A4,
        const int* __restrict__ seg, int total, float* __restrict__ dst) {
    const int b  = blockIdx.x / CPS;
    const int c  = blockIdx.x % CPS;
    const int s0 = lower_bound64(seg, total, b);
    const int s1 = lower_bound64(seg, total, b + 1);
    const int chunk = (s1 - s0 + CPS - 1) / CPS;
    const int r0 = s0 + c * chunk;
    const int r1 = min(r0 + chunk, s1);
    const int t  = threadIdx.x;
    const int dq = t & 31;
    const int g  = t >> 5;
    float4 acc[8];
    #pragma unroll
    for (int h = 0; h < 8; ++h) acc[h] = make_float4(0.f, 0.f, 0.f, 0.f);
    float wsum[8] = {0.f};
    for (int i = r0 + g; i < r1; i += 8) {
        float4 f = F[(size_t)i * (D / 4) + dq];
        const float* a = (const float*)&A4[(size_t)i * 2];
        #pragma unroll
        for (int h = 0; h < 8; ++h) {
            acc[h].x = fmaf(f.x, a[h], acc[h].x);
            acc[h].y = fmaf(f.y, a[h], acc[h].y);
            acc[h].z = fmaf(f.z, a[h], acc[h].z);
            acc[h].w = fmaf(f.w, a[h], acc[h].w);
            wsum[h] += a[h];
        }
    }
    #pragma unroll
    for (int h = 0; h < 8; ++h) {
        float* o = dst + (b * H + h) * D + dq * 4;
        atomicAdd(o + 0, acc[h].x); atomicAdd(o + 1, acc[h].y);
        atomicAdd(o + 2, acc[h].z); atomicAdd(o + 3, acc[h].w);
        if (dq == 0) atomicAdd(dst + B * H * D + b * H + h, wsum[h]);
    }
}

__global__ void finalize_kernel(float* __restrict__ out) {
    int idx = blockIdx.x * blockDim.x + threadIdx.x;
    if (idx >= B * H * D) return;
    float denom = out[B * H * D + (idx >> 7)];
    float r = (denom == 0.0f) ? 0.0f : out[idx] / denom;
    if (isnan(r)) r = 1e-5f;
    out[idx] = r;
}

extern "C" void kernel_launch(void* const* d_in, const int* in_sizes, int n_in,
                              void* d_out, int out_size, void* d_ws, size_t ws_size,
                              hipStream_t stream) {
    const float* features = (const float*)d_in[0];
    const float* att      = (const float*)d_in[1];
    const int*   seg      = (const int*)d_in[2];
    const int    total    = in_sizes[2];

    float* partial = (float*)d_ws;
    float* out     = (float*)d_out;

    const size_t needed = (size_t)B * CPS * PSTRIDE * sizeof(float);

    if (ws_size >= needed) {
        accum_kernel<<<B * CPS, 256, 0, stream>>>(
            (const float4*)features, (const float4*)att, seg, total, partial);
        reduce_kernel<<<B * H, 128, 0, stream>>>(partial, out);
    } else {
        hipMemsetAsync(d_out, 0, (size_t)out_size * sizeof(float), stream);
        accum_atomic_kernel<<<B * CPS, 256, 0, stream>>>(
            (const float4*)features, (const float4*)att, seg, total, out);
        finalize_kernel<<<(B * H * D + 255) / 256, 256, 0, stream>>>(out);
    }
}